// Round 16
// baseline (689.802 us; speedup 1.0000x reference)
//
#include <hip/hip_runtime.h>
#include <math.h>

// Problem constants (match reference setup_inputs)
constexpr int B = 2;
constexpr int N = 4096;
constexpr int C = 32;
constexpr int D = 256;
constexpr int K = 16;
constexpr int NW = N / 32;   // adjacency bitmask words per row = 128
constexpr int CAP = 128;     // max neighbors per row (16 out + in-degree)
constexpr int ROWS = B * N;  // 8192

__device__ __forceinline__ unsigned short f2bf(float f) {   // RNE f32 -> bf16
    unsigned u = __float_as_uint(f);
    return (unsigned short)((u + 0x7fffu + ((u >> 16) & 1u)) >> 16);
}
__device__ __forceinline__ float bflo(unsigned u) { return __uint_as_float(u << 16); }
__device__ __forceinline__ float bfhi(unsigned u) { return __uint_as_float(u & 0xffff0000u); }

// ---------------------------------------------------------------------------
// Kernel 1: per-row preprocess: centers(+sqnorm or INF if invalid), and a
// PRE-NORMALIZED bf16 copy of the feature row. One wave per row; also zeroes
// the adjacency bitmask.
__global__ void pre_kernel(const float* __restrict__ rois,
                           const float* __restrict__ feats,
                           float4* __restrict__ centers4,
                           unsigned short* __restrict__ fnbf,
                           uint2* __restrict__ adj_zero) {
    const int t = threadIdx.x;
    const int wid = t >> 6, lane = t & 63;
    const int r = blockIdx.x * 4 + wid;

    // zero adjacency: 2048 blocks * 256 threads == ROWS*NW/2 uint2 elements
    adj_zero[blockIdx.x * 256 + t] = make_uint2(0u, 0u);

    if (r >= ROWS) return;

    const float4* f4 = reinterpret_cast<const float4*>(feats) + (size_t)r * (D / 4);
    float4 v = f4[lane];
    float ss = v.x * v.x + v.y * v.y + v.z * v.z + v.w * v.w;
#pragma unroll
    for (int off = 32; off; off >>= 1) ss += __shfl_xor(ss, off);

    const float invn = 1.0f / fmaxf(sqrtf(ss), 1e-6f);
    unsigned u0 = (unsigned)f2bf(v.x * invn) | ((unsigned)f2bf(v.y * invn) << 16);
    unsigned u1 = (unsigned)f2bf(v.z * invn) | ((unsigned)f2bf(v.w * invn) << 16);
    *reinterpret_cast<uint2*>(fnbf + (size_t)r * D + lane * 4) = make_uint2(u0, u1);

    if (lane == 0) {
        const float* rp = rois + (size_t)r * 6;
        float a0 = rp[0], a1 = rp[1], a2 = rp[2], a3 = rp[3], a4 = rp[4], a5 = rp[5];
        float cx = (a0 + a3) * 0.5f, cy = (a1 + a4) * 0.5f, cz = (a2 + a5) * 0.5f;
        float sq = cx * cx + cy * cy + cz * cz;
        float s = fabsf(a0) + fabsf(a1) + fabsf(a2) + fabsf(a3) + fabsf(a4) + fabsf(a5);
        centers4[r] = make_float4(cx, cy, cz, (s > 0.0f) ? sq : INFINITY);
    }
}

// ---------------------------------------------------------------------------
// Kernel 2: exact 16-NN, chunk-in-register structure (see R8 notes).
__global__ __launch_bounds__(1024, 8) void knn_kernel(const float4* __restrict__ centers4,
                                                      unsigned* __restrict__ adj) {
    __shared__ float4 s_c[N];                        // 64 KB
    __shared__ unsigned s_pm[16][64];                // 4 KB subset-min bits
    __shared__ unsigned long long s_buf[16][64];     // 8 KB survivor keys
    __shared__ int s_cnt[16];
    __shared__ float s_tau[16];

    const int t = threadIdx.x;
    const int lane = t & 63;
    const int wv = t >> 6;
    const int r0 = blockIdx.x * 16;        // first global row of block
    const int nbase = r0 & (N - 1);        // first in-batch row index
    const int gbase = r0 - nbase;          // batch offset (0 or N)

    if (t < 16) s_cnt[t] = 0;
    ((unsigned*)s_pm)[t] = 0x7F800000u;    // +INF bits (1024 entries exactly)
    for (int i = t; i < N; i += 1024) s_c[i] = centers4[gbase + i];
    __syncthreads();

    // wave-owned candidate chunk, kept in registers
    float4 cmv[4];
    int    mv[4];
#pragma unroll
    for (int u = 0; u < 4; ++u) {
        mv[u] = (wv << 8) + (u << 6) + lane;
        cmv[u] = s_c[mv[u]];
    }

    // ---- pass 1: per-row min over this lane's 4 candidates; merge via atomicMin ----
#pragma unroll 4
    for (int rr = 0; rr < 16; ++rr) {
        const int nrow = nbase + rr;
        const float4 rc = s_c[nrow];       // same-address broadcast, conflict-free
        float mn = INFINITY;
#pragma unroll
        for (int u = 0; u < 4; ++u) {
            float dist = fmaxf(rc.w + cmv[u].w -
                               2.0f * (rc.x * cmv[u].x + rc.y * cmv[u].y + rc.z * cmv[u].z), 0.0f);
            mn = fminf(mn, (mv[u] == nrow) ? INFINITY : dist);
        }
        atomicMin(&s_pm[rr][lane], __float_as_uint(mn));
    }
    __syncthreads();

    // ---- tau per row: wave rr sorts its row's 64 subset minima ----
    {
        float v = __uint_as_float(s_pm[wv][lane]);
#pragma unroll
        for (int k = 2; k <= 64; k <<= 1) {
#pragma unroll
            for (int j = k >> 1; j > 0; j >>= 1) {
                float o = __shfl_xor(v, j);
                bool take_min = (((lane & j) == 0) == ((lane & k) == 0));
                v = take_min ? fminf(v, o) : fmaxf(v, o);
            }
        }
        if (lane == 15) s_tau[wv] = v;     // 16th smallest
    }
    __syncthreads();

    // ---- pass 2: append survivors from the register chunk for all 16 rows ----
#pragma unroll 4
    for (int rr = 0; rr < 16; ++rr) {
        const int nrow = nbase + rr;
        const float tau = s_tau[rr];
        const float4 rc = s_c[nrow];
#pragma unroll
        for (int u = 0; u < 4; ++u) {
            float dist = fmaxf(rc.w + cmv[u].w -
                               2.0f * (rc.x * cmv[u].x + rc.y * cmv[u].y + rc.z * cmv[u].z), 0.0f);
            if (dist <= tau && mv[u] != nrow) {
                int pos = atomicAdd(&s_cnt[rr], 1);
                if (pos < 64)
                    s_buf[rr][pos] = ((unsigned long long)__float_as_uint(dist) << 32)
                                     | (unsigned)mv[u];
            }
        }
    }
    __syncthreads();

    // ---- selection: wave rr owns row rr ----
    const int rg = r0 + wv;                // global row
    const int n = nbase + wv;              // in-batch row
    const int cnt = s_cnt[wv];

    int my_sel = -1;
    if (cnt <= 64) {
        unsigned long long key = (lane < cnt) ? s_buf[wv][lane] : ~0ull;
#pragma unroll
        for (int k = 2; k <= 64; k <<= 1) {
#pragma unroll
            for (int j = k >> 1; j > 0; j >>= 1) {
                unsigned long long o = __shfl_xor(key, j);
                bool take_min = (((lane & j) == 0) == ((lane & k) == 0));
                unsigned long long mn = (key < o) ? key : o;
                unsigned long long mx = (key < o) ? o : key;
                key = take_min ? mn : mx;
            }
        }
        if (lane < K && key != ~0ull) my_sel = (int)(unsigned)key;
    } else {
        // exact fallback: 16 rounds of full rescan-argmin over LDS table
        const float4 cq = s_c[n];
        unsigned long long removed = 0ull;
        for (int round = 0; round < K; ++round) {
            float bd = INFINITY; int bi = 0x7FFFFFFF;
            for (int j = 0; j < 64; ++j) {
                const int m = lane + (j << 6);
                float4 cm = s_c[m];
                float dist = fmaxf(cq.w + cm.w -
                                   2.0f * (cq.x * cm.x + cq.y * cm.y + cq.z * cm.z), 0.0f);
                bool skip = ((removed >> j) & 1ull) || (m == n);
                if (!skip && dist < bd) { bd = dist; bi = m; }
            }
            float md = bd;
#pragma unroll
            for (int off = 32; off; off >>= 1) md = fminf(md, __shfl_xor(md, off));
            if (md == INFINITY) break;
            int kk = (bd == md) ? bi : 0x7FFFFFFF;
#pragma unroll
            for (int off = 32; off; off >>= 1) kk = min(kk, __shfl_xor(kk, off));
            if (lane == round) my_sel = kk;
            if (kk == bi) removed |= 1ull << (bi >> 6);
        }
    }

    if (my_sel >= 0) {
        atomicOr(&adj[(size_t)rg * NW + (my_sel >> 5)], 1u << (my_sel & 31));
        atomicOr(&adj[(size_t)(gbase + my_sel) * NW + (n >> 5)], 1u << (n & 31));
    }
}

// ---------------------------------------------------------------------------
// Kernel 3: build weighted neighbor lists — BARRIER-FREE, ONE WAVE PER ROW
// (see R13 notes). Fused: initial softmax moments mu0 on lanes 0..31.
__global__ __launch_bounds__(256) void build_kernel(const unsigned short* __restrict__ fnbf,
                             const float4* __restrict__ centers4,
                             const unsigned* __restrict__ adj,
                             uint2* __restrict__ nbr,
                             int* __restrict__ nbr_cnt,
                             const float* __restrict__ raw_sigma,
                             const float* __restrict__ logits,
                             float2* __restrict__ mu0) {
    const int t = threadIdx.x;
    const int lane = t & 63;
    const int wv = t >> 6;          // 0..3
    const int r = blockIdx.x * 4 + wv;
    const int base = r - (r & (N - 1));

    __shared__ float4 s_q[4][16 * 5];   // per-wave padded Q: idx 5e+s (+1 pad/e)
    __shared__ int    s_list[4][CAP];
    __shared__ float  s_w[4][CAP];

    // ---- adjacency compaction (wave-local, ascending => deterministic) ----
    uint2 wpair = *reinterpret_cast<const uint2*>(adj + (size_t)r * NW + 2 * lane);
    const int pc = __popc(wpair.x) + __popc(wpair.y);
    int sc = pc;
#pragma unroll
    for (int off = 1; off < 64; off <<= 1) {
        int o = __shfl_up(sc, off);
        if (lane >= off) sc += o;
    }
    const int total = __shfl(sc, 63);
    const int cnt = total > CAP ? CAP : total;
    int o = sc - pc;                   // exclusive prefix
    {
        unsigned ww = wpair.x; int mb = lane * 64;
        while (ww) { int b = __ffs(ww) - 1; if (o < CAP) s_list[wv][o] = mb + b; ++o; ww &= ww - 1; }
        ww = wpair.y; mb = lane * 64 + 32;
        while (ww) { int b = __ffs(ww) - 1; if (o < CAP) s_list[wv][o] = mb + b; ++o; ww &= ww - 1; }
    }

    // ---- stage q row (bf16 -> f32) into padded per-wave layout ----
    {
        uint2 qw = *reinterpret_cast<const uint2*>(fnbf + (size_t)r * D + 4 * lane);
        float4 qv = make_float4(bflo(qw.x), bfhi(qw.x), bflo(qw.y), bfhi(qw.y));
        const int e = (lane & 31) >> 1;
        const int s = ((lane >> 5) << 1) | (lane & 1);
        s_q[wv][5 * e + s] = qv;
    }

    const float rs = raw_sigma[0];
    const float sigma = fmaxf(log1pf(expf(rs)), 1e-6f);
    const float nhalf_inv_s2 = -0.5f / (sigma * sigma);
    const float4 cq = centers4[r];
    const uint4* fn4 = reinterpret_cast<const uint4*>(fnbf);

    // ---- gather: 16-lane groups, 4 neighbors per wave per step ----
    {
        const int g = lane >> 4;    // neighbor slot (0..3)
        const int e = lane & 15;    // element slice (0..15)
        for (int i0 = 0; i0 < cnt; i0 += 4) {
            const int i = i0 + g;
            const bool act = (i < cnt);
            const int gm = base + s_list[wv][act ? i : 0];
            uint4 a = fn4[(size_t)gm * 32 + e];        // elems [8e, 8e+8)
            uint4 b = fn4[(size_t)gm * 32 + 16 + e];   // elems [128+8e, 128+8e+8)
            float4 cm = centers4[gm];                  // broadcast within group
            float4 qa0 = s_q[wv][5 * e + 0], qa1 = s_q[wv][5 * e + 1];
            float4 qb0 = s_q[wv][5 * e + 2], qb1 = s_q[wv][5 * e + 3];
            float p = bflo(a.x) * qa0.x + bfhi(a.x) * qa0.y
                    + bflo(a.y) * qa0.z + bfhi(a.y) * qa0.w
                    + bflo(a.z) * qa1.x + bfhi(a.z) * qa1.y
                    + bflo(a.w) * qa1.z + bfhi(a.w) * qa1.w
                    + bflo(b.x) * qb0.x + bfhi(b.x) * qb0.y
                    + bflo(b.y) * qb0.z + bfhi(b.y) * qb0.w
                    + bflo(b.z) * qb1.x + bfhi(b.z) * qb1.y
                    + bflo(b.w) * qb1.z + bfhi(b.w) * qb1.w;
#pragma unroll
            for (int off = 1; off < 16; off <<= 1) p += __shfl_xor(p, off);
            float aff = fminf(fmaxf((p + 1.0f) * 0.5f, 0.0f), 1.0f);
            float dist = fmaxf(cq.w + cm.w -
                               2.0f * (cq.x * cm.x + cq.y * cm.y + cq.z * cm.z), 0.0f);
            if (e == 0 && act) s_w[wv][i] = expf(dist * nhalf_inv_s2) * aff;
        }
    }

    // ---- wave-local weight sum (deterministic) + normalize + write ----
    float ps = 0.0f;
    for (int i = lane; i < cnt; i += 64) ps += s_w[wv][i];
#pragma unroll
    for (int off = 32; off; off >>= 1) ps += __shfl_xor(ps, off);
    const float inv_sum = 1.0f / fmaxf(ps, 1e-6f);

    for (int i = lane; i < cnt; i += 64) {
        nbr[(size_t)r * CAP + i] = make_uint2((unsigned)s_list[wv][i],
                                              __float_as_uint(s_w[wv][i] * inv_sum));
    }
    if (lane == 0) nbr_cnt[r] = cnt;

    // ---- fused initial softmax moments (lanes 0..31) ----
    if (lane < C) {
        float x = logits[(size_t)r * C + lane];
        float mx = x;
#pragma unroll
        for (int off = 16; off; off >>= 1) mx = fmaxf(mx, __shfl_xor(mx, off, 32));
        float e = expf(x - mx);
        const float fc = (float)lane;
        float s0 = e, s1 = e * fc, s2 = e * fc * fc;
#pragma unroll
        for (int off = 16; off; off >>= 1) {
            s0 += __shfl_xor(s0, off, 32);
            s1 += __shfl_xor(s1, off, 32);
            s2 += __shfl_xor(s2, off, 32);
        }
        if (lane == 0) mu0[r] = make_float2(s1 / s0, s2 / s0);
    }
}

// ---------------------------------------------------------------------------
// Kernel 4: ALL 5 mean-field iterations in ONE dispatch using a manual
// device-scope grid barrier (monotonic atomic counter, reset to 0 by
// hipMemsetAsync before each launch — deterministic). Plain kernel (no
// cooperative launch; R8 showed that breaks graph replay). Co-residency:
// 1024 blocks x 4 waves = 4096 waves vs 8192 slots (no LDS, low VGPR).
// Visibility: writers __threadfence() before __syncthreads(); thread 0
// arrives via atomicAdd and spins on device-scope atomic reads; fence +
// __syncthreads() after. Per-iteration math identical to R14's iter_kernel.
__global__ __launch_bounds__(256) void iters_kernel(const float* __restrict__ logits,
                                                    const uint2* __restrict__ nbr,
                                                    const int* __restrict__ nbr_cnt,
                                                    float2* __restrict__ mu_a,
                                                    float2* __restrict__ mu_b,
                                                    float* __restrict__ out,
                                                    const float* __restrict__ raw_smooth,
                                                    unsigned* __restrict__ bar) {
    const int t = threadIdx.x;
    const int r = blockIdx.x * 8 + (t >> 5);
    const int c = t & 31;
    const int base = r - (r & (N - 1));
    const float smooth = log1pf(expf(raw_smooth[0]));

    const int cnt = nbr_cnt[r];
    const uint2* np = nbr + (size_t)r * CAP;
    const float x = logits[(size_t)r * C + c];
    const float fc = (float)c;

    float2* mi = mu_a;
    float2* mo = mu_b;

    for (int it = 0; it < 5; ++it) {
        float m0 = 0.0f, m1 = 0.0f, m2 = 0.0f;
        for (int j = c; j < cnt; j += 32) {
            uint2 e = np[j];
            float w = __uint_as_float(e.y);
            float2 mu = mi[base + (int)e.x];
            m0 += w; m1 += w * mu.x; m2 += w * mu.y;
        }
#pragma unroll
        for (int off = 16; off; off >>= 1) {
            m0 += __shfl_xor(m0, off, 32);
            m1 += __shfl_xor(m1, off, 32);
            m2 += __shfl_xor(m2, off, 32);
        }

        float pw = (m2 - 2.0f * fc * m1 + fc * fc * m0) * (1.0f / 961.0f);
        float refined = x - smooth * pw;

        if (it == 4) {
            out[(size_t)r * C + c] = refined;
        } else {
            float mx = refined;
#pragma unroll
            for (int off = 16; off; off >>= 1) mx = fmaxf(mx, __shfl_xor(mx, off, 32));
            float e = expf(refined - mx);
            float s0 = e, s1 = e * fc, s2 = e * fc * fc;
#pragma unroll
            for (int off = 16; off; off >>= 1) {
                s0 += __shfl_xor(s0, off, 32);
                s1 += __shfl_xor(s1, off, 32);
                s2 += __shfl_xor(s2, off, 32);
            }
            if (c == 0) mo[r] = make_float2(s1 / s0, s2 / s0);

            // ---- grid barrier (monotonic counter; phase it+1) ----
            __threadfence();               // release this thread's mu store
            __syncthreads();               // all block stores fenced before arrival
            if (t == 0) {
                atomicAdd(bar, 1u);
                const unsigned target = (unsigned)((it + 1) * gridDim.x);
                while (atomicAdd(bar, 0u) < target) {
                    __builtin_amdgcn_s_sleep(8);
                }
            }
            __syncthreads();
            __threadfence();               // acquire before reading others' mu

            float2* tmp = mi; mi = mo; mo = tmp;
        }
    }
}

// ---------------------------------------------------------------------------
extern "C" void kernel_launch(void* const* d_in, const int* in_sizes, int n_in,
                              void* d_out, int out_size, void* d_ws, size_t ws_size,
                              hipStream_t stream) {
    const float* logits     = (const float*)d_in[0];
    const float* rois       = (const float*)d_in[1];
    const float* feats      = (const float*)d_in[2];
    const float* raw_sigma  = (const float*)d_in[3];
    const float* raw_smooth = (const float*)d_in[4];
    float* out = (float*)d_out;

    char* ws = (char*)d_ws;
    size_t off = 0;
    auto alloc = [&](size_t bytes) -> void* {
        void* p = ws + off;
        off += (bytes + 255) & ~(size_t)255;
        return p;
    };
    float4*         centers4 = (float4*)        alloc((size_t)ROWS * sizeof(float4));
    unsigned short* fnbf     = (unsigned short*)alloc((size_t)ROWS * D * 2);
    unsigned*       adj      = (unsigned*)      alloc((size_t)ROWS * NW * 4);
    uint2*          nbr      = (uint2*)         alloc((size_t)ROWS * CAP * 8);
    int*            nbr_cnt  = (int*)           alloc((size_t)ROWS * 4);
    float2*         mu_a     = (float2*)        alloc((size_t)ROWS * 8);
    float2*         mu_b     = (float2*)        alloc((size_t)ROWS * 8);
    unsigned*       bar      = (unsigned*)      alloc(256);

    hipMemsetAsync(bar, 0, 4, stream);
    pre_kernel<<<ROWS / 4, 256, 0, stream>>>(rois, feats, centers4, fnbf, (uint2*)adj);
    knn_kernel<<<ROWS / 16, 1024, 0, stream>>>(centers4, adj);
    build_kernel<<<ROWS / 4, 256, 0, stream>>>(fnbf, centers4, adj,
                                               nbr, nbr_cnt, raw_sigma, logits, mu_a);
    iters_kernel<<<ROWS / 8, 256, 0, stream>>>(logits, nbr, nbr_cnt,
                                               mu_a, mu_b, out, raw_smooth, bar);
}

// Round 17
// 76.657 us; speedup vs baseline: 8.9986x; 8.9986x over previous
//
#include <hip/hip_runtime.h>
#include <math.h>

// Problem constants (match reference setup_inputs)
constexpr int B = 2;
constexpr int N = 4096;
constexpr int C = 32;
constexpr int D = 256;
constexpr int K = 16;
constexpr int NW = N / 32;   // adjacency bitmask words per row = 128
constexpr int CAP = 128;     // max neighbors per row (16 out + in-degree)
constexpr int ROWS = B * N;  // 8192

__device__ __forceinline__ unsigned short f2bf(float f) {   // RNE f32 -> bf16
    unsigned u = __float_as_uint(f);
    return (unsigned short)((u + 0x7fffu + ((u >> 16) & 1u)) >> 16);
}
__device__ __forceinline__ float bflo(unsigned u) { return __uint_as_float(u << 16); }
__device__ __forceinline__ float bfhi(unsigned u) { return __uint_as_float(u & 0xffff0000u); }

// ---------------------------------------------------------------------------
// Kernel 1: per-row preprocess: centers(+sqnorm or INF if invalid), and a
// PRE-NORMALIZED bf16 copy of the feature row. One wave per row; also zeroes
// the adjacency bitmask.
__global__ void pre_kernel(const float* __restrict__ rois,
                           const float* __restrict__ feats,
                           float4* __restrict__ centers4,
                           unsigned short* __restrict__ fnbf,
                           uint2* __restrict__ adj_zero) {
    const int t = threadIdx.x;
    const int wid = t >> 6, lane = t & 63;
    const int r = blockIdx.x * 4 + wid;

    // zero adjacency: 2048 blocks * 256 threads == ROWS*NW/2 uint2 elements
    adj_zero[blockIdx.x * 256 + t] = make_uint2(0u, 0u);

    if (r >= ROWS) return;

    const float4* f4 = reinterpret_cast<const float4*>(feats) + (size_t)r * (D / 4);
    float4 v = f4[lane];
    float ss = v.x * v.x + v.y * v.y + v.z * v.z + v.w * v.w;
#pragma unroll
    for (int off = 32; off; off >>= 1) ss += __shfl_xor(ss, off);

    const float invn = 1.0f / fmaxf(sqrtf(ss), 1e-6f);
    unsigned u0 = (unsigned)f2bf(v.x * invn) | ((unsigned)f2bf(v.y * invn) << 16);
    unsigned u1 = (unsigned)f2bf(v.z * invn) | ((unsigned)f2bf(v.w * invn) << 16);
    *reinterpret_cast<uint2*>(fnbf + (size_t)r * D + lane * 4) = make_uint2(u0, u1);

    if (lane == 0) {
        const float* rp = rois + (size_t)r * 6;
        float a0 = rp[0], a1 = rp[1], a2 = rp[2], a3 = rp[3], a4 = rp[4], a5 = rp[5];
        float cx = (a0 + a3) * 0.5f, cy = (a1 + a4) * 0.5f, cz = (a2 + a5) * 0.5f;
        float sq = cx * cx + cy * cy + cz * cz;
        float s = fabsf(a0) + fabsf(a1) + fabsf(a2) + fabsf(a3) + fabsf(a4) + fabsf(a5);
        centers4[r] = make_float4(cx, cy, cz, (s > 0.0f) ? sq : INFINITY);
    }
}

// ---------------------------------------------------------------------------
// Kernel 2: exact 16-NN, chunk-in-register structure (see R8 notes).
__global__ __launch_bounds__(1024, 8) void knn_kernel(const float4* __restrict__ centers4,
                                                      unsigned* __restrict__ adj) {
    __shared__ float4 s_c[N];                        // 64 KB
    __shared__ unsigned s_pm[16][64];                // 4 KB subset-min bits
    __shared__ unsigned long long s_buf[16][64];     // 8 KB survivor keys
    __shared__ int s_cnt[16];
    __shared__ float s_tau[16];

    const int t = threadIdx.x;
    const int lane = t & 63;
    const int wv = t >> 6;
    const int r0 = blockIdx.x * 16;        // first global row of block
    const int nbase = r0 & (N - 1);        // first in-batch row index
    const int gbase = r0 - nbase;          // batch offset (0 or N)

    if (t < 16) s_cnt[t] = 0;
    ((unsigned*)s_pm)[t] = 0x7F800000u;    // +INF bits (1024 entries exactly)
    for (int i = t; i < N; i += 1024) s_c[i] = centers4[gbase + i];
    __syncthreads();

    // wave-owned candidate chunk, kept in registers
    float4 cmv[4];
    int    mv[4];
#pragma unroll
    for (int u = 0; u < 4; ++u) {
        mv[u] = (wv << 8) + (u << 6) + lane;
        cmv[u] = s_c[mv[u]];
    }

    // ---- pass 1: per-row min over this lane's 4 candidates; merge via atomicMin ----
#pragma unroll 4
    for (int rr = 0; rr < 16; ++rr) {
        const int nrow = nbase + rr;
        const float4 rc = s_c[nrow];       // same-address broadcast, conflict-free
        float mn = INFINITY;
#pragma unroll
        for (int u = 0; u < 4; ++u) {
            float dist = fmaxf(rc.w + cmv[u].w -
                               2.0f * (rc.x * cmv[u].x + rc.y * cmv[u].y + rc.z * cmv[u].z), 0.0f);
            mn = fminf(mn, (mv[u] == nrow) ? INFINITY : dist);
        }
        atomicMin(&s_pm[rr][lane], __float_as_uint(mn));
    }
    __syncthreads();

    // ---- tau per row: wave rr sorts its row's 64 subset minima ----
    {
        float v = __uint_as_float(s_pm[wv][lane]);
#pragma unroll
        for (int k = 2; k <= 64; k <<= 1) {
#pragma unroll
            for (int j = k >> 1; j > 0; j >>= 1) {
                float o = __shfl_xor(v, j);
                bool take_min = (((lane & j) == 0) == ((lane & k) == 0));
                v = take_min ? fminf(v, o) : fmaxf(v, o);
            }
        }
        if (lane == 15) s_tau[wv] = v;     // 16th smallest
    }
    __syncthreads();

    // ---- pass 2: append survivors from the register chunk for all 16 rows ----
#pragma unroll 4
    for (int rr = 0; rr < 16; ++rr) {
        const int nrow = nbase + rr;
        const float tau = s_tau[rr];
        const float4 rc = s_c[nrow];
#pragma unroll
        for (int u = 0; u < 4; ++u) {
            float dist = fmaxf(rc.w + cmv[u].w -
                               2.0f * (rc.x * cmv[u].x + rc.y * cmv[u].y + rc.z * cmv[u].z), 0.0f);
            if (dist <= tau && mv[u] != nrow) {
                int pos = atomicAdd(&s_cnt[rr], 1);
                if (pos < 64)
                    s_buf[rr][pos] = ((unsigned long long)__float_as_uint(dist) << 32)
                                     | (unsigned)mv[u];
            }
        }
    }
    __syncthreads();

    // ---- selection: wave rr owns row rr ----
    const int rg = r0 + wv;                // global row
    const int n = nbase + wv;              // in-batch row
    const int cnt = s_cnt[wv];

    int my_sel = -1;
    if (cnt <= 64) {
        unsigned long long key = (lane < cnt) ? s_buf[wv][lane] : ~0ull;
#pragma unroll
        for (int k = 2; k <= 64; k <<= 1) {
#pragma unroll
            for (int j = k >> 1; j > 0; j >>= 1) {
                unsigned long long o = __shfl_xor(key, j);
                bool take_min = (((lane & j) == 0) == ((lane & k) == 0));
                unsigned long long mn = (key < o) ? key : o;
                unsigned long long mx = (key < o) ? o : key;
                key = take_min ? mn : mx;
            }
        }
        if (lane < K && key != ~0ull) my_sel = (int)(unsigned)key;
    } else {
        // exact fallback: 16 rounds of full rescan-argmin over LDS table
        const float4 cq = s_c[n];
        unsigned long long removed = 0ull;
        for (int round = 0; round < K; ++round) {
            float bd = INFINITY; int bi = 0x7FFFFFFF;
            for (int j = 0; j < 64; ++j) {
                const int m = lane + (j << 6);
                float4 cm = s_c[m];
                float dist = fmaxf(cq.w + cm.w -
                                   2.0f * (cq.x * cm.x + cq.y * cm.y + cq.z * cm.z), 0.0f);
                bool skip = ((removed >> j) & 1ull) || (m == n);
                if (!skip && dist < bd) { bd = dist; bi = m; }
            }
            float md = bd;
#pragma unroll
            for (int off = 32; off; off >>= 1) md = fminf(md, __shfl_xor(md, off));
            if (md == INFINITY) break;
            int kk = (bd == md) ? bi : 0x7FFFFFFF;
#pragma unroll
            for (int off = 32; off; off >>= 1) kk = min(kk, __shfl_xor(kk, off));
            if (lane == round) my_sel = kk;
            if (kk == bi) removed |= 1ull << (bi >> 6);
        }
    }

    if (my_sel >= 0) {
        atomicOr(&adj[(size_t)rg * NW + (my_sel >> 5)], 1u << (my_sel & 31));
        atomicOr(&adj[(size_t)(gbase + my_sel) * NW + (n >> 5)], 1u << (n & 31));
    }
}

// ---------------------------------------------------------------------------
// Kernel 3: build weighted neighbor lists — barrier-free, one wave per row
// (R13 structure) — WITH ITERATION 1 FUSED. mu0 of any neighbor depends only
// on its logits (softmax moments of raw logits), so inside the gather loop
// each 16-lane group also loads the neighbor's 32 logits and computes its
// mu0 (4-step group reduces), accumulating Sum w*(1, mu1, mu2). All 16 lanes
// of a group hold identical contributions -> wave-sum / 16 is exact. Build
// then applies iteration 1 for its own row and writes mu1 directly.
__global__ __launch_bounds__(256) void build_kernel(const unsigned short* __restrict__ fnbf,
                             const float4* __restrict__ centers4,
                             const unsigned* __restrict__ adj,
                             uint2* __restrict__ nbr,
                             int* __restrict__ nbr_cnt,
                             const float* __restrict__ raw_sigma,
                             const float* __restrict__ logits,
                             const float* __restrict__ raw_smooth,
                             float2* __restrict__ mu1) {
    const int t = threadIdx.x;
    const int lane = t & 63;
    const int wv = t >> 6;          // 0..3
    const int r = blockIdx.x * 4 + wv;
    const int base = r - (r & (N - 1));

    __shared__ float4 s_q[4][16 * 5];   // per-wave padded Q: idx 5e+s (+1 pad/e)
    __shared__ int    s_list[4][CAP];
    __shared__ float  s_w[4][CAP];

    // ---- adjacency compaction (wave-local, ascending => deterministic) ----
    uint2 wpair = *reinterpret_cast<const uint2*>(adj + (size_t)r * NW + 2 * lane);
    const int pc = __popc(wpair.x) + __popc(wpair.y);
    int sc = pc;
#pragma unroll
    for (int off = 1; off < 64; off <<= 1) {
        int o = __shfl_up(sc, off);
        if (lane >= off) sc += o;
    }
    const int total = __shfl(sc, 63);
    const int cnt = total > CAP ? CAP : total;
    int o = sc - pc;                   // exclusive prefix
    {
        unsigned ww = wpair.x; int mb = lane * 64;
        while (ww) { int b = __ffs(ww) - 1; if (o < CAP) s_list[wv][o] = mb + b; ++o; ww &= ww - 1; }
        ww = wpair.y; mb = lane * 64 + 32;
        while (ww) { int b = __ffs(ww) - 1; if (o < CAP) s_list[wv][o] = mb + b; ++o; ww &= ww - 1; }
    }

    // ---- stage q row (bf16 -> f32) into padded per-wave layout ----
    {
        uint2 qw = *reinterpret_cast<const uint2*>(fnbf + (size_t)r * D + 4 * lane);
        float4 qv = make_float4(bflo(qw.x), bfhi(qw.x), bflo(qw.y), bfhi(qw.y));
        const int e = (lane & 31) >> 1;
        const int s = ((lane >> 5) << 1) | (lane & 1);
        s_q[wv][5 * e + s] = qv;
    }

    const float rs = raw_sigma[0];
    const float sigma = fmaxf(log1pf(expf(rs)), 1e-6f);
    const float nhalf_inv_s2 = -0.5f / (sigma * sigma);
    const float smooth = log1pf(expf(raw_smooth[0]));
    const float4 cq = centers4[r];
    const uint4* fn4 = reinterpret_cast<const uint4*>(fnbf);

    // iteration-1 accumulators (Sum over neighbors of w * (1, mu0x, mu0y));
    // every lane of a 16-lane group adds identical values -> /16 at the end.
    float am0 = 0.0f, am1 = 0.0f, am2 = 0.0f;

    // ---- gather: 16-lane groups, 4 neighbors per wave per step ----
    {
        const int g = lane >> 4;    // neighbor slot (0..3)
        const int e = lane & 15;    // element slice (0..15)
        for (int i0 = 0; i0 < cnt; i0 += 4) {
            const int i = i0 + g;
            const bool act = (i < cnt);
            const int gm = base + s_list[wv][act ? i : 0];
            uint4 a = fn4[(size_t)gm * 32 + e];        // elems [8e, 8e+8)
            uint4 b = fn4[(size_t)gm * 32 + 16 + e];   // elems [128+8e, 128+8e+8)
            float4 cm = centers4[gm];                  // broadcast within group
            float2 lg = *reinterpret_cast<const float2*>(logits + (size_t)gm * C + 2 * e);
            float4 qa0 = s_q[wv][5 * e + 0], qa1 = s_q[wv][5 * e + 1];
            float4 qb0 = s_q[wv][5 * e + 2], qb1 = s_q[wv][5 * e + 3];
            float p = bflo(a.x) * qa0.x + bfhi(a.x) * qa0.y
                    + bflo(a.y) * qa0.z + bfhi(a.y) * qa0.w
                    + bflo(a.z) * qa1.x + bfhi(a.z) * qa1.y
                    + bflo(a.w) * qa1.z + bfhi(a.w) * qa1.w
                    + bflo(b.x) * qb0.x + bfhi(b.x) * qb0.y
                    + bflo(b.y) * qb0.z + bfhi(b.y) * qb0.w
                    + bflo(b.z) * qb1.x + bfhi(b.z) * qb1.y
                    + bflo(b.w) * qb1.z + bfhi(b.w) * qb1.w;
#pragma unroll
            for (int off = 1; off < 16; off <<= 1) p += __shfl_xor(p, off);
            float aff = fminf(fmaxf((p + 1.0f) * 0.5f, 0.0f), 1.0f);
            float dist = fmaxf(cq.w + cm.w -
                               2.0f * (cq.x * cm.x + cq.y * cm.y + cq.z * cm.z), 0.0f);
            float w = expf(dist * nhalf_inv_s2) * aff;   // all 16 lanes
            if (e == 0 && act) s_w[wv][i] = w;

            // neighbor mu0 from its logits (group softmax moments)
            float mx = fmaxf(lg.x, lg.y);
#pragma unroll
            for (int off = 1; off < 16; off <<= 1) mx = fmaxf(mx, __shfl_xor(mx, off));
            float e0 = expf(lg.x - mx), e1 = expf(lg.y - mx);
            const float fc0 = (float)(2 * e), fc1 = (float)(2 * e + 1);
            float s0 = e0 + e1;
            float s1 = e0 * fc0 + e1 * fc1;
            float s2 = e0 * fc0 * fc0 + e1 * fc1 * fc1;
#pragma unroll
            for (int off = 1; off < 16; off <<= 1) {
                s0 += __shfl_xor(s0, off);
                s1 += __shfl_xor(s1, off);
                s2 += __shfl_xor(s2, off);
            }
            if (act) {
                am0 += w;
                am1 += w * (s1 / s0);
                am2 += w * (s2 / s0);
            }
        }
    }

    // ---- wave-local weight sum (deterministic) + normalize + write ----
    float ps = 0.0f;
    for (int i = lane; i < cnt; i += 64) ps += s_w[wv][i];
#pragma unroll
    for (int off = 32; off; off >>= 1) ps += __shfl_xor(ps, off);
    const float inv_sum = 1.0f / fmaxf(ps, 1e-6f);

    for (int i = lane; i < cnt; i += 64) {
        nbr[(size_t)r * CAP + i] = make_uint2((unsigned)s_list[wv][i],
                                              __float_as_uint(s_w[wv][i] * inv_sum));
    }
    if (lane == 0) nbr_cnt[r] = cnt;

    // ---- iteration 1 for own row: reduce accumulators, refined, mu1 ----
#pragma unroll
    for (int off = 32; off; off >>= 1) {
        am0 += __shfl_xor(am0, off);
        am1 += __shfl_xor(am1, off);
        am2 += __shfl_xor(am2, off);
    }
    const float m0 = am0 * 0.0625f * inv_sum;   // /16 exact, then normalize
    const float m1 = am1 * 0.0625f * inv_sum;
    const float m2 = am2 * 0.0625f * inv_sum;

    if (lane < C) {
        const float fc = (float)lane;
        float pw = (m2 - 2.0f * fc * m1 + fc * fc * m0) * (1.0f / 961.0f);
        float refined = logits[(size_t)r * C + lane] - smooth * pw;
        float mx = refined;
#pragma unroll
        for (int off = 16; off; off >>= 1) mx = fmaxf(mx, __shfl_xor(mx, off, 32));
        float e = expf(refined - mx);
        float s0 = e, s1 = e * fc, s2 = e * fc * fc;
#pragma unroll
        for (int off = 16; off; off >>= 1) {
            s0 += __shfl_xor(s0, off, 32);
            s1 += __shfl_xor(s1, off, 32);
            s2 += __shfl_xor(s2, off, 32);
        }
        if (lane == 0) mu1[r] = make_float2(s1 / s0, s2 / s0);
    }
}

// ---------------------------------------------------------------------------
// Kernel 4: one mean-field iteration, MOMENT-COMPRESSED (R9 structure).
__global__ void iter_kernel(const float* __restrict__ logits,
                            const uint2* __restrict__ nbr,
                            const int* __restrict__ nbr_cnt,
                            const float2* __restrict__ mu_in,
                            float2* __restrict__ mu_out,
                            float* __restrict__ out,
                            const float* __restrict__ raw_smooth,
                            int last) {
    const int t = threadIdx.x;
    const int r = blockIdx.x * 8 + (t >> 5);
    const int c = t & 31;
    const int base = r - (r & (N - 1));
    const float smooth = log1pf(expf(raw_smooth[0]));

    const int cnt = nbr_cnt[r];
    const uint2* np = nbr + (size_t)r * CAP;

    float m0 = 0.0f, m1 = 0.0f, m2 = 0.0f;
    for (int j = c; j < cnt; j += 32) {
        uint2 e = np[j];
        float w = __uint_as_float(e.y);
        float2 mu = mu_in[base + (int)e.x];
        m0 += w; m1 += w * mu.x; m2 += w * mu.y;
    }
#pragma unroll
    for (int off = 16; off; off >>= 1) {
        m0 += __shfl_xor(m0, off, 32);
        m1 += __shfl_xor(m1, off, 32);
        m2 += __shfl_xor(m2, off, 32);
    }

    const float fc = (float)c;
    float pw = (m2 - 2.0f * fc * m1 + fc * fc * m0) * (1.0f / 961.0f);
    float refined = logits[(size_t)r * C + c] - smooth * pw;

    if (last) {
        out[(size_t)r * C + c] = refined;
        return;
    }

    float mx = refined;
#pragma unroll
    for (int off = 16; off; off >>= 1) mx = fmaxf(mx, __shfl_xor(mx, off, 32));
    float e = expf(refined - mx);
    float s0 = e, s1 = e * fc, s2 = e * fc * fc;
#pragma unroll
    for (int off = 16; off; off >>= 1) {
        s0 += __shfl_xor(s0, off, 32);
        s1 += __shfl_xor(s1, off, 32);
        s2 += __shfl_xor(s2, off, 32);
    }
    if (c == 0) mu_out[r] = make_float2(s1 / s0, s2 / s0);
}

// ---------------------------------------------------------------------------
extern "C" void kernel_launch(void* const* d_in, const int* in_sizes, int n_in,
                              void* d_out, int out_size, void* d_ws, size_t ws_size,
                              hipStream_t stream) {
    const float* logits     = (const float*)d_in[0];
    const float* rois       = (const float*)d_in[1];
    const float* feats      = (const float*)d_in[2];
    const float* raw_sigma  = (const float*)d_in[3];
    const float* raw_smooth = (const float*)d_in[4];
    float* out = (float*)d_out;

    char* ws = (char*)d_ws;
    size_t off = 0;
    auto alloc = [&](size_t bytes) -> void* {
        void* p = ws + off;
        off += (bytes + 255) & ~(size_t)255;
        return p;
    };
    float4*         centers4 = (float4*)        alloc((size_t)ROWS * sizeof(float4));
    unsigned short* fnbf     = (unsigned short*)alloc((size_t)ROWS * D * 2);
    unsigned*       adj      = (unsigned*)      alloc((size_t)ROWS * NW * 4);
    uint2*          nbr      = (uint2*)         alloc((size_t)ROWS * CAP * 8);
    int*            nbr_cnt  = (int*)           alloc((size_t)ROWS * 4);
    float2*         mu_a     = (float2*)        alloc((size_t)ROWS * 8);
    float2*         mu_b     = (float2*)        alloc((size_t)ROWS * 8);

    pre_kernel<<<ROWS / 4, 256, 0, stream>>>(rois, feats, centers4, fnbf, (uint2*)adj);
    knn_kernel<<<ROWS / 16, 1024, 0, stream>>>(centers4, adj);
    // build + iteration 1 fused -> mu_a holds mu1
    build_kernel<<<ROWS / 4, 256, 0, stream>>>(fnbf, centers4, adj,
                                               nbr, nbr_cnt, raw_sigma, logits,
                                               raw_smooth, mu_a);
    // iterations 2..4 (mu updates), iteration 5 writes refined logits
    iter_kernel<<<ROWS / 8, 256, 0, stream>>>(logits, nbr, nbr_cnt, mu_a, mu_b, out, raw_smooth, 0);
    iter_kernel<<<ROWS / 8, 256, 0, stream>>>(logits, nbr, nbr_cnt, mu_b, mu_a, out, raw_smooth, 0);
    iter_kernel<<<ROWS / 8, 256, 0, stream>>>(logits, nbr, nbr_cnt, mu_a, mu_b, out, raw_smooth, 0);
    iter_kernel<<<ROWS / 8, 256, 0, stream>>>(logits, nbr, nbr_cnt, mu_b, mu_a, out, raw_smooth, 1);
}

// Round 18
// 72.381 us; speedup vs baseline: 9.5301x; 1.0591x over previous
//
#include <hip/hip_runtime.h>
#include <math.h>

// Problem constants (match reference setup_inputs)
constexpr int B = 2;
constexpr int N = 4096;
constexpr int C = 32;
constexpr int D = 256;
constexpr int K = 16;
constexpr int NW = N / 32;   // adjacency bitmask words per row = 128
constexpr int CAP = 128;     // max neighbors per row (16 out + in-degree)
constexpr int ROWS = B * N;  // 8192

__device__ __forceinline__ unsigned short f2bf(float f) {   // RNE f32 -> bf16
    unsigned u = __float_as_uint(f);
    return (unsigned short)((u + 0x7fffu + ((u >> 16) & 1u)) >> 16);
}
__device__ __forceinline__ float bflo(unsigned u) { return __uint_as_float(u << 16); }
__device__ __forceinline__ float bfhi(unsigned u) { return __uint_as_float(u & 0xffff0000u); }

// ---------------------------------------------------------------------------
// Kernel 1: per-row preprocess: centers(+sqnorm or INF if invalid), a
// PRE-NORMALIZED bf16 copy of the feature row, and mu0[r] = softmax moments
// of the row's raw logits (per-row, so build's it1 fusion costs one broadcast
// load per edge instead of a per-edge softmax — R17 lesson). One wave per
// row; also zeroes the adjacency bitmask.
__global__ void pre_kernel(const float* __restrict__ rois,
                           const float* __restrict__ feats,
                           const float* __restrict__ logits,
                           float4* __restrict__ centers4,
                           unsigned short* __restrict__ fnbf,
                           float2* __restrict__ mu0,
                           uint2* __restrict__ adj_zero) {
    const int t = threadIdx.x;
    const int wid = t >> 6, lane = t & 63;
    const int r = blockIdx.x * 4 + wid;

    // zero adjacency: 2048 blocks * 256 threads == ROWS*NW/2 uint2 elements
    adj_zero[blockIdx.x * 256 + t] = make_uint2(0u, 0u);

    if (r >= ROWS) return;

    const float4* f4 = reinterpret_cast<const float4*>(feats) + (size_t)r * (D / 4);
    float4 v = f4[lane];
    float ss = v.x * v.x + v.y * v.y + v.z * v.z + v.w * v.w;
#pragma unroll
    for (int off = 32; off; off >>= 1) ss += __shfl_xor(ss, off);

    const float invn = 1.0f / fmaxf(sqrtf(ss), 1e-6f);
    unsigned u0 = (unsigned)f2bf(v.x * invn) | ((unsigned)f2bf(v.y * invn) << 16);
    unsigned u1 = (unsigned)f2bf(v.z * invn) | ((unsigned)f2bf(v.w * invn) << 16);
    *reinterpret_cast<uint2*>(fnbf + (size_t)r * D + lane * 4) = make_uint2(u0, u1);

    // softmax moments of own logits (lanes 0..31)
    if (lane < C) {
        float x = logits[(size_t)r * C + lane];
        float mx = x;
#pragma unroll
        for (int off = 16; off; off >>= 1) mx = fmaxf(mx, __shfl_xor(mx, off, 32));
        float e = expf(x - mx);
        const float fc = (float)lane;
        float s0 = e, s1 = e * fc, s2 = e * fc * fc;
#pragma unroll
        for (int off = 16; off; off >>= 1) {
            s0 += __shfl_xor(s0, off, 32);
            s1 += __shfl_xor(s1, off, 32);
            s2 += __shfl_xor(s2, off, 32);
        }
        if (lane == 0) mu0[r] = make_float2(s1 / s0, s2 / s0);
    }

    if (lane == 0) {
        const float* rp = rois + (size_t)r * 6;
        float a0 = rp[0], a1 = rp[1], a2 = rp[2], a3 = rp[3], a4 = rp[4], a5 = rp[5];
        float cx = (a0 + a3) * 0.5f, cy = (a1 + a4) * 0.5f, cz = (a2 + a5) * 0.5f;
        float sq = cx * cx + cy * cy + cz * cz;
        float s = fabsf(a0) + fabsf(a1) + fabsf(a2) + fabsf(a3) + fabsf(a4) + fabsf(a5);
        centers4[r] = make_float4(cx, cy, cz, (s > 0.0f) ? sq : INFINITY);
    }
}

// ---------------------------------------------------------------------------
// Kernel 2: exact 16-NN, chunk-in-register structure (see R8 notes).
__global__ __launch_bounds__(1024, 8) void knn_kernel(const float4* __restrict__ centers4,
                                                      unsigned* __restrict__ adj) {
    __shared__ float4 s_c[N];                        // 64 KB
    __shared__ unsigned s_pm[16][64];                // 4 KB subset-min bits
    __shared__ unsigned long long s_buf[16][64];     // 8 KB survivor keys
    __shared__ int s_cnt[16];
    __shared__ float s_tau[16];

    const int t = threadIdx.x;
    const int lane = t & 63;
    const int wv = t >> 6;
    const int r0 = blockIdx.x * 16;        // first global row of block
    const int nbase = r0 & (N - 1);        // first in-batch row index
    const int gbase = r0 - nbase;          // batch offset (0 or N)

    if (t < 16) s_cnt[t] = 0;
    ((unsigned*)s_pm)[t] = 0x7F800000u;    // +INF bits (1024 entries exactly)
    for (int i = t; i < N; i += 1024) s_c[i] = centers4[gbase + i];
    __syncthreads();

    // wave-owned candidate chunk, kept in registers
    float4 cmv[4];
    int    mv[4];
#pragma unroll
    for (int u = 0; u < 4; ++u) {
        mv[u] = (wv << 8) + (u << 6) + lane;
        cmv[u] = s_c[mv[u]];
    }

    // ---- pass 1: per-row min over this lane's 4 candidates; merge via atomicMin ----
#pragma unroll 4
    for (int rr = 0; rr < 16; ++rr) {
        const int nrow = nbase + rr;
        const float4 rc = s_c[nrow];       // same-address broadcast, conflict-free
        float mn = INFINITY;
#pragma unroll
        for (int u = 0; u < 4; ++u) {
            float dist = fmaxf(rc.w + cmv[u].w -
                               2.0f * (rc.x * cmv[u].x + rc.y * cmv[u].y + rc.z * cmv[u].z), 0.0f);
            mn = fminf(mn, (mv[u] == nrow) ? INFINITY : dist);
        }
        atomicMin(&s_pm[rr][lane], __float_as_uint(mn));
    }
    __syncthreads();

    // ---- tau per row: wave rr sorts its row's 64 subset minima ----
    {
        float v = __uint_as_float(s_pm[wv][lane]);
#pragma unroll
        for (int k = 2; k <= 64; k <<= 1) {
#pragma unroll
            for (int j = k >> 1; j > 0; j >>= 1) {
                float o = __shfl_xor(v, j);
                bool take_min = (((lane & j) == 0) == ((lane & k) == 0));
                v = take_min ? fminf(v, o) : fmaxf(v, o);
            }
        }
        if (lane == 15) s_tau[wv] = v;     // 16th smallest
    }
    __syncthreads();

    // ---- pass 2: append survivors from the register chunk for all 16 rows ----
#pragma unroll 4
    for (int rr = 0; rr < 16; ++rr) {
        const int nrow = nbase + rr;
        const float tau = s_tau[rr];
        const float4 rc = s_c[nrow];
#pragma unroll
        for (int u = 0; u < 4; ++u) {
            float dist = fmaxf(rc.w + cmv[u].w -
                               2.0f * (rc.x * cmv[u].x + rc.y * cmv[u].y + rc.z * cmv[u].z), 0.0f);
            if (dist <= tau && mv[u] != nrow) {
                int pos = atomicAdd(&s_cnt[rr], 1);
                if (pos < 64)
                    s_buf[rr][pos] = ((unsigned long long)__float_as_uint(dist) << 32)
                                     | (unsigned)mv[u];
            }
        }
    }
    __syncthreads();

    // ---- selection: wave rr owns row rr ----
    const int rg = r0 + wv;                // global row
    const int n = nbase + wv;              // in-batch row
    const int cnt = s_cnt[wv];

    int my_sel = -1;
    if (cnt <= 64) {
        unsigned long long key = (lane < cnt) ? s_buf[wv][lane] : ~0ull;
#pragma unroll
        for (int k = 2; k <= 64; k <<= 1) {
#pragma unroll
            for (int j = k >> 1; j > 0; j >>= 1) {
                unsigned long long o = __shfl_xor(key, j);
                bool take_min = (((lane & j) == 0) == ((lane & k) == 0));
                unsigned long long mn = (key < o) ? key : o;
                unsigned long long mx = (key < o) ? o : key;
                key = take_min ? mn : mx;
            }
        }
        if (lane < K && key != ~0ull) my_sel = (int)(unsigned)key;
    } else {
        // exact fallback: 16 rounds of full rescan-argmin over LDS table
        const float4 cq = s_c[n];
        unsigned long long removed = 0ull;
        for (int round = 0; round < K; ++round) {
            float bd = INFINITY; int bi = 0x7FFFFFFF;
            for (int j = 0; j < 64; ++j) {
                const int m = lane + (j << 6);
                float4 cm = s_c[m];
                float dist = fmaxf(cq.w + cm.w -
                                   2.0f * (cq.x * cm.x + cq.y * cm.y + cq.z * cm.z), 0.0f);
                bool skip = ((removed >> j) & 1ull) || (m == n);
                if (!skip && dist < bd) { bd = dist; bi = m; }
            }
            float md = bd;
#pragma unroll
            for (int off = 32; off; off >>= 1) md = fminf(md, __shfl_xor(md, off));
            if (md == INFINITY) break;
            int kk = (bd == md) ? bi : 0x7FFFFFFF;
#pragma unroll
            for (int off = 32; off; off >>= 1) kk = min(kk, __shfl_xor(kk, off));
            if (lane == round) my_sel = kk;
            if (kk == bi) removed |= 1ull << (bi >> 6);
        }
    }

    if (my_sel >= 0) {
        atomicOr(&adj[(size_t)rg * NW + (my_sel >> 5)], 1u << (my_sel & 31));
        atomicOr(&adj[(size_t)(gbase + my_sel) * NW + (n >> 5)], 1u << (n & 31));
    }
}

// ---------------------------------------------------------------------------
// Kernel 3: build weighted neighbor lists — barrier-free, one wave per row
// (R13 structure) + it1 fused CHEAPLY: mu0[gm] is a precomputed float2
// (from pre_kernel), so the gather loop adds one 8B broadcast load + 3 FMAs
// per neighbor; group-redundant accumulation /16 exact. Emits mu1 directly.
__global__ __launch_bounds__(256) void build_kernel(const unsigned short* __restrict__ fnbf,
                             const float4* __restrict__ centers4,
                             const unsigned* __restrict__ adj,
                             const float2* __restrict__ mu0,
                             uint2* __restrict__ nbr,
                             int* __restrict__ nbr_cnt,
                             const float* __restrict__ raw_sigma,
                             const float* __restrict__ logits,
                             const float* __restrict__ raw_smooth,
                             float2* __restrict__ mu1) {
    const int t = threadIdx.x;
    const int lane = t & 63;
    const int wv = t >> 6;          // 0..3
    const int r = blockIdx.x * 4 + wv;
    const int base = r - (r & (N - 1));

    __shared__ float4 s_q[4][16 * 5];   // per-wave padded Q: idx 5e+s (+1 pad/e)
    __shared__ int    s_list[4][CAP];
    __shared__ float  s_w[4][CAP];

    // ---- adjacency compaction (wave-local, ascending => deterministic) ----
    uint2 wpair = *reinterpret_cast<const uint2*>(adj + (size_t)r * NW + 2 * lane);
    const int pc = __popc(wpair.x) + __popc(wpair.y);
    int sc = pc;
#pragma unroll
    for (int off = 1; off < 64; off <<= 1) {
        int o = __shfl_up(sc, off);
        if (lane >= off) sc += o;
    }
    const int total = __shfl(sc, 63);
    const int cnt = total > CAP ? CAP : total;
    int o = sc - pc;                   // exclusive prefix
    {
        unsigned ww = wpair.x; int mb = lane * 64;
        while (ww) { int b = __ffs(ww) - 1; if (o < CAP) s_list[wv][o] = mb + b; ++o; ww &= ww - 1; }
        ww = wpair.y; mb = lane * 64 + 32;
        while (ww) { int b = __ffs(ww) - 1; if (o < CAP) s_list[wv][o] = mb + b; ++o; ww &= ww - 1; }
    }

    // ---- stage q row (bf16 -> f32) into padded per-wave layout ----
    {
        uint2 qw = *reinterpret_cast<const uint2*>(fnbf + (size_t)r * D + 4 * lane);
        float4 qv = make_float4(bflo(qw.x), bfhi(qw.x), bflo(qw.y), bfhi(qw.y));
        const int e = (lane & 31) >> 1;
        const int s = ((lane >> 5) << 1) | (lane & 1);
        s_q[wv][5 * e + s] = qv;
    }

    const float rs = raw_sigma[0];
    const float sigma = fmaxf(log1pf(expf(rs)), 1e-6f);
    const float nhalf_inv_s2 = -0.5f / (sigma * sigma);
    const float smooth = log1pf(expf(raw_smooth[0]));
    const float4 cq = centers4[r];
    const uint4* fn4 = reinterpret_cast<const uint4*>(fnbf);

    // it1 accumulators (group-redundant; /16 exact at the end)
    float am0 = 0.0f, am1 = 0.0f, am2 = 0.0f;

    // ---- gather: 16-lane groups, 4 neighbors per wave per step ----
    {
        const int g = lane >> 4;    // neighbor slot (0..3)
        const int e = lane & 15;    // element slice (0..15)
        for (int i0 = 0; i0 < cnt; i0 += 4) {
            const int i = i0 + g;
            const bool act = (i < cnt);
            const int gm = base + s_list[wv][act ? i : 0];
            uint4 a = fn4[(size_t)gm * 32 + e];        // elems [8e, 8e+8)
            uint4 b = fn4[(size_t)gm * 32 + 16 + e];   // elems [128+8e, 128+8e+8)
            float4 cm = centers4[gm];                  // broadcast within group
            float2 nmu = mu0[gm];                      // broadcast within group
            float4 qa0 = s_q[wv][5 * e + 0], qa1 = s_q[wv][5 * e + 1];
            float4 qb0 = s_q[wv][5 * e + 2], qb1 = s_q[wv][5 * e + 3];
            float p = bflo(a.x) * qa0.x + bfhi(a.x) * qa0.y
                    + bflo(a.y) * qa0.z + bfhi(a.y) * qa0.w
                    + bflo(a.z) * qa1.x + bfhi(a.z) * qa1.y
                    + bflo(a.w) * qa1.z + bfhi(a.w) * qa1.w
                    + bflo(b.x) * qb0.x + bfhi(b.x) * qb0.y
                    + bflo(b.y) * qb0.z + bfhi(b.y) * qb0.w
                    + bflo(b.z) * qb1.x + bfhi(b.z) * qb1.y
                    + bflo(b.w) * qb1.z + bfhi(b.w) * qb1.w;
#pragma unroll
            for (int off = 1; off < 16; off <<= 1) p += __shfl_xor(p, off);
            float aff = fminf(fmaxf((p + 1.0f) * 0.5f, 0.0f), 1.0f);
            float dist = fmaxf(cq.w + cm.w -
                               2.0f * (cq.x * cm.x + cq.y * cm.y + cq.z * cm.z), 0.0f);
            float w = expf(dist * nhalf_inv_s2) * aff;
            if (e == 0 && act) s_w[wv][i] = w;
            if (act) {
                am0 += w;
                am1 += w * nmu.x;
                am2 += w * nmu.y;
            }
        }
    }

    // ---- wave-local weight sum (deterministic) + normalize + write ----
    float ps = 0.0f;
    for (int i = lane; i < cnt; i += 64) ps += s_w[wv][i];
#pragma unroll
    for (int off = 32; off; off >>= 1) ps += __shfl_xor(ps, off);
    const float inv_sum = 1.0f / fmaxf(ps, 1e-6f);

    for (int i = lane; i < cnt; i += 64) {
        nbr[(size_t)r * CAP + i] = make_uint2((unsigned)s_list[wv][i],
                                              __float_as_uint(s_w[wv][i] * inv_sum));
    }
    if (lane == 0) nbr_cnt[r] = cnt;

    // ---- it1 for own row: reduce accumulators (/16 exact), refined, mu1 ----
#pragma unroll
    for (int off = 32; off; off >>= 1) {
        am0 += __shfl_xor(am0, off);
        am1 += __shfl_xor(am1, off);
        am2 += __shfl_xor(am2, off);
    }
    const float m0 = am0 * 0.0625f * inv_sum;
    const float m1 = am1 * 0.0625f * inv_sum;
    const float m2 = am2 * 0.0625f * inv_sum;

    if (lane < C) {
        const float fc = (float)lane;
        float pw = (m2 - 2.0f * fc * m1 + fc * fc * m0) * (1.0f / 961.0f);
        float refined = logits[(size_t)r * C + lane] - smooth * pw;
        float mx = refined;
#pragma unroll
        for (int off = 16; off; off >>= 1) mx = fmaxf(mx, __shfl_xor(mx, off, 32));
        float e = expf(refined - mx);
        float s0 = e, s1 = e * fc, s2 = e * fc * fc;
#pragma unroll
        for (int off = 16; off; off >>= 1) {
            s0 += __shfl_xor(s0, off, 32);
            s1 += __shfl_xor(s1, off, 32);
            s2 += __shfl_xor(s2, off, 32);
        }
        if (lane == 0) mu1[r] = make_float2(s1 / s0, s2 / s0);
    }
}

// ---------------------------------------------------------------------------
// Kernel 4: one mean-field iteration, MOMENT-COMPRESSED (R9 structure).
__global__ void iter_kernel(const float* __restrict__ logits,
                            const uint2* __restrict__ nbr,
                            const int* __restrict__ nbr_cnt,
                            const float2* __restrict__ mu_in,
                            float2* __restrict__ mu_out,
                            float* __restrict__ out,
                            const float* __restrict__ raw_smooth,
                            int last) {
    const int t = threadIdx.x;
    const int r = blockIdx.x * 8 + (t >> 5);
    const int c = t & 31;
    const int base = r - (r & (N - 1));
    const float smooth = log1pf(expf(raw_smooth[0]));

    const int cnt = nbr_cnt[r];
    const uint2* np = nbr + (size_t)r * CAP;

    float m0 = 0.0f, m1 = 0.0f, m2 = 0.0f;
    for (int j = c; j < cnt; j += 32) {
        uint2 e = np[j];
        float w = __uint_as_float(e.y);
        float2 mu = mu_in[base + (int)e.x];
        m0 += w; m1 += w * mu.x; m2 += w * mu.y;
    }
#pragma unroll
    for (int off = 16; off; off >>= 1) {
        m0 += __shfl_xor(m0, off, 32);
        m1 += __shfl_xor(m1, off, 32);
        m2 += __shfl_xor(m2, off, 32);
    }

    const float fc = (float)c;
    float pw = (m2 - 2.0f * fc * m1 + fc * fc * m0) * (1.0f / 961.0f);
    float refined = logits[(size_t)r * C + c] - smooth * pw;

    if (last) {
        out[(size_t)r * C + c] = refined;
        return;
    }

    float mx = refined;
#pragma unroll
    for (int off = 16; off; off >>= 1) mx = fmaxf(mx, __shfl_xor(mx, off, 32));
    float e = expf(refined - mx);
    float s0 = e, s1 = e * fc, s2 = e * fc * fc;
#pragma unroll
    for (int off = 16; off; off >>= 1) {
        s0 += __shfl_xor(s0, off, 32);
        s1 += __shfl_xor(s1, off, 32);
        s2 += __shfl_xor(s2, off, 32);
    }
    if (c == 0) mu_out[r] = make_float2(s1 / s0, s2 / s0);
}

// ---------------------------------------------------------------------------
extern "C" void kernel_launch(void* const* d_in, const int* in_sizes, int n_in,
                              void* d_out, int out_size, void* d_ws, size_t ws_size,
                              hipStream_t stream) {
    const float* logits     = (const float*)d_in[0];
    const float* rois       = (const float*)d_in[1];
    const float* feats      = (const float*)d_in[2];
    const float* raw_sigma  = (const float*)d_in[3];
    const float* raw_smooth = (const float*)d_in[4];
    float* out = (float*)d_out;

    char* ws = (char*)d_ws;
    size_t off = 0;
    auto alloc = [&](size_t bytes) -> void* {
        void* p = ws + off;
        off += (bytes + 255) & ~(size_t)255;
        return p;
    };
    float4*         centers4 = (float4*)        alloc((size_t)ROWS * sizeof(float4));
    unsigned short* fnbf     = (unsigned short*)alloc((size_t)ROWS * D * 2);
    unsigned*       adj      = (unsigned*)      alloc((size_t)ROWS * NW * 4);
    uint2*          nbr      = (uint2*)         alloc((size_t)ROWS * CAP * 8);
    int*            nbr_cnt  = (int*)           alloc((size_t)ROWS * 4);
    float2*         mu_0     = (float2*)        alloc((size_t)ROWS * 8);
    float2*         mu_a     = (float2*)        alloc((size_t)ROWS * 8);
    float2*         mu_b     = (float2*)        alloc((size_t)ROWS * 8);

    pre_kernel<<<ROWS / 4, 256, 0, stream>>>(rois, feats, logits, centers4, fnbf,
                                             mu_0, (uint2*)adj);
    knn_kernel<<<ROWS / 16, 1024, 0, stream>>>(centers4, adj);
    // build + iteration 1 (cheap mu0-broadcast form) -> mu_a holds mu1
    build_kernel<<<ROWS / 4, 256, 0, stream>>>(fnbf, centers4, adj, mu_0,
                                               nbr, nbr_cnt, raw_sigma, logits,
                                               raw_smooth, mu_a);
    // iterations 2..4 (mu updates), iteration 5 writes refined logits
    iter_kernel<<<ROWS / 8, 256, 0, stream>>>(logits, nbr, nbr_cnt, mu_a, mu_b, out, raw_smooth, 0);
    iter_kernel<<<ROWS / 8, 256, 0, stream>>>(logits, nbr, nbr_cnt, mu_b, mu_a, out, raw_smooth, 0);
    iter_kernel<<<ROWS / 8, 256, 0, stream>>>(logits, nbr, nbr_cnt, mu_a, mu_b, out, raw_smooth, 0);
    iter_kernel<<<ROWS / 8, 256, 0, stream>>>(logits, nbr, nbr_cnt, mu_b, mu_a, out, raw_smooth, 1);
}